// Round 9
// baseline (180.002 us; speedup 1.0000x reference)
//
#include <hip/hip_runtime.h>

// out[b,o,n] = max_d |x[b,d,n] - w[o,d]| + bias[o]
// B=64, CIN=1024, COUT=1024, N=49. Pixels P = B*N = 3136.
//
// Round-9: rounds 6/8 post-mortem showed BOTH w-paths stall ~125 cyc/tile
// because per-tile compute (~110 cyc) < load latency (~250 cyc): depth-1
// prefetch can't cover. Fix: 4 PIXELS PER LANE -> per-tile compute ~416 cyc
// (64 pk + 64 max3) >> latency, so prefetch-1 covers fully even at low
// occupancy. w back on the scalar pipe (s_load, zero VALU/LDS/VMEM cost);
// x: 16 dword loads/tile, issued a full tile ahead. No LDS, no barriers.
// Inner mix per (ch, k-pair): v_pk_add_f32(neg) + v_max3(|.|,|.|).

typedef float v2f __attribute__((ext_vector_type(2)));
typedef float v4f __attribute__((ext_vector_type(4)));

constexpr int CIN  = 1024;
constexpr int COUT = 1024;
constexpr int NN   = 49;
constexpr int P    = 3136;
constexpr int CPW  = 8;             // channels per wave
constexpr int WPB  = 2;             // waves per block (128 threads)
constexpr int CPB  = CPW * WPB;     // 16 channels per block
constexpr int PIX  = 4;             // pixels per lane
constexpr int PT   = 64 * PIX;      // 256 pixels per tile
constexpr int NPT  = (P + PT - 1) / PT;  // 13 (last tile ragged: 64 px)
constexpr int NTL  = CIN / 4;       // 256 k-tiles

#define PKSUB(d, wp, xp) \
    asm("v_pk_add_f32 %0, %1, %2 neg_lo:[0,1] neg_hi:[0,1]" \
        : "=v"(d) : "s"(wp), "v"(xp))
#define AMAX3(a, lo, hi) \
    asm("v_max3_f32 %0, %0, |%1|, |%2|" : "+v"(a) : "v"(lo), "v"(hi))

__global__ __launch_bounds__(128) void ndist_kernel(
    const float* __restrict__ x, const float* __restrict__ w,
    const float* __restrict__ bias, float* __restrict__ out)
{
    const int lane = threadIdx.x & 63;
    const int wid  = __builtin_amdgcn_readfirstlane(threadIdx.x >> 6);

    const int o0    = blockIdx.x * CPB + wid * CPW;   // wave channel base
    const int pbase = blockIdx.y * PT;                // tile pixel base

    // Per pixel-slot state. Slot validity (pbase + i*64 < P) is lane-INDEPENDENT
    // (P and all bases are multiples of 64) -> scalar predication, no divergence.
    int b[PIX], n[PIX];
    const float* xp[PIX];
#pragma unroll
    for (int i = 0; i < PIX; ++i) {
        const bool valid = (pbase + i * 64) < P;           // uniform
        const int  pi    = (valid ? pbase + i * 64 : pbase) + lane;  // clamp reads
        b[i]  = pi / NN;
        n[i]  = pi - b[i] * NN;
        xp[i] = x + (size_t)b[i] * (CIN * NN) + n[i];
    }

    const float* __restrict__ wb = w + (size_t)o0 * CIN;   // uniform -> s_load

    float acc[CPW][PIX];
#pragma unroll
    for (int c = 0; c < CPW; ++c)
#pragma unroll
        for (int i = 0; i < PIX; ++i) acc[c][i] = 0.0f;    // |diff| >= 0

    v2f xA[PIX][2], xB[PIX][2];   // x k-pairs, 4 pixels (VGPR)
    v2f wA[CPW][2], wB[CPW][2];   // w k-pairs, 8 channels (SGPR via s_load_dwordx4)

#define LOAD_X(dst, kt) do {                                     \
        _Pragma("unroll")                                        \
        for (int i = 0; i < PIX; ++i) {                          \
            float a0 = xp[i][((kt) * 4 + 0) * NN];               \
            float a1 = xp[i][((kt) * 4 + 1) * NN];               \
            float a2 = xp[i][((kt) * 4 + 2) * NN];               \
            float a3 = xp[i][((kt) * 4 + 3) * NN];               \
            dst[i][0] = (v2f){a0, a1};                           \
            dst[i][1] = (v2f){a2, a3};                           \
        }                                                        \
    } while (0)

#define LOAD_W(dst, kt) do {                                     \
        _Pragma("unroll")                                        \
        for (int c = 0; c < CPW; ++c) {                          \
            v4f t = *(const v4f*)(wb + (size_t)c * CIN + (size_t)(kt) * 4); \
            dst[c][0] = (v2f){t.x, t.y};                         \
            dst[c][1] = (v2f){t.z, t.w};                         \
        }                                                        \
    } while (0)

    // 64 pk + 64 max3 = ~416 cyc of straight-line independent VALU per tile
#define COMPUTE(xv, wv) do {                                     \
        _Pragma("unroll")                                        \
        for (int c = 0; c < CPW; ++c)                            \
        _Pragma("unroll")                                        \
        for (int i = 0; i < PIX; ++i) {                          \
            v2f d0, d1;                                          \
            PKSUB(d0, wv[c][0], xv[i][0]);                       \
            PKSUB(d1, wv[c][1], xv[i][1]);                       \
            AMAX3(acc[c][i], d0.x, d0.y);                        \
            AMAX3(acc[c][i], d1.x, d1.y);                        \
        }                                                        \
    } while (0)

    LOAD_W(wA, 0);
    LOAD_X(xA, 0);

    for (int kt = 0; kt < NTL; kt += 2) {
        // prefetch tile kt+1 while computing kt (compute >> latency now)
        LOAD_W(wB, kt + 1);
        LOAD_X(xB, kt + 1);
        COMPUTE(xA, wA);

        const int ktn = (kt + 2) & (NTL - 1);   // wrap on last iter: harmless
        LOAD_W(wA, ktn);
        LOAD_X(xA, ktn);
        COMPUTE(xB, wB);
    }

    // epilogue: predication is block-uniform per slot
#pragma unroll
    for (int i = 0; i < PIX; ++i) {
        if ((pbase + i * 64) < P) {
#pragma unroll
            for (int c = 0; c < CPW; ++c) {
                const int o = o0 + c;
                out[((size_t)b[i] * COUT + o) * NN + n[i]] = acc[c][i] + bias[o];
            }
        }
    }
}

extern "C" void kernel_launch(void* const* d_in, const int* in_sizes, int n_in,
                              void* d_out, int out_size, void* d_ws, size_t ws_size,
                              hipStream_t stream) {
    const float* x    = (const float*)d_in[0];
    const float* w    = (const float*)d_in[1];
    const float* bias = (const float*)d_in[2];
    float* out        = (float*)d_out;

    dim3 grid(COUT / CPB, NPT);   // (64 channel-groups, 13 pixel-tiles) = 832 blocks
    ndist_kernel<<<grid, 128, 0, stream>>>(x, w, bias, out);
}